// Round 6
// baseline (39.486 us; speedup 1.0000x reference)
//
#include <hip/hip_runtime.h>

// PadMaskedSequence, fused single kernel with persistent blocks + atomic
// work-stealing. d_out layout: x_ [B*T*D] f32, then lens [B] as float.
//
// Work quantum: (batch b, chunk of ROWS=32 input rows). 2048 quanta, 512
// blocks (2/CU): each block takes chunk blockIdx.x statically, then steals
// via atomicAdd on a counter in d_ws (memset to 0 each launch). Stealing
// bounds per-CU load imbalance at ~one quantum. Per grabbed chunk the block
// recomputes prefix P (rows before chunk) and total L from the L2-resident
// mask row in one packed 64-bit reduction, copies selected rows to output
// rows P+i, and zero-pads its share of rows >= L. Every output row written
// exactly once per launch; no ordering assumptions.

typedef float f32x4 __attribute__((ext_vector_type(4)));

#define BLK 256
#define NW (BLK / 64)
#define ROWS 32

__global__ __launch_bounds__(BLK) void pad_masked_steal(
    const float* __restrict__ x,
    const int* __restrict__ mask,
    float* __restrict__ out,
    float* __restrict__ lens_f,
    unsigned* __restrict__ counter,
    int T, int D4, int CPB, int total) {

    const int tid = threadIdx.x;
    const int lane = tid & 63;
    const int wave = tid >> 6;

    __shared__ unsigned long long wred[NW];
    __shared__ int sChunk;

    int id = blockIdx.x;  // static first assignment (no atomic storm at t=0)

    while (id < total) {
        const int b = id / CPB;
        const int c = id - b * CPB;
        const int j0 = c * ROWS;
        const int* mrow = mask + (size_t)b * T;

        // ---- packed popcount: pre = sum mask[0:j0), all = sum mask[0:T) ----
        // j0 % ROWS == 0 and e % 4 == 0, so an int4 never straddles j0.
        int pre = 0, all = 0;
        for (int e = tid * 4; e < T; e += BLK * 4) {
            const int4 mv = *reinterpret_cast<const int4*>(mrow + e);
            const int s4 = (mv.x != 0) + (mv.y != 0) + (mv.z != 0) + (mv.w != 0);
            all += s4;
            if (e < j0) pre += s4;
        }
        unsigned long long packed = (unsigned long long)(unsigned)pre |
                                    ((unsigned long long)(unsigned)all << 32);
        #pragma unroll
        for (int off = 32; off; off >>= 1) packed += __shfl_xor(packed, off);
        if (lane == 0) wred[wave] = packed;
        __syncthreads();
        unsigned long long tot = 0;
        #pragma unroll
        for (int w = 0; w < NW; ++w) tot += wred[w];
        const int P = (int)(tot & 0xffffffffull);  // output base row of chunk
        const int L = (int)(tot >> 32);            // lens[b]

        if (c == 0 && tid == 0) lens_f[b] = (float)L;

        // ---- selected rows of this chunk (wave-uniform bitmask, ROWS<=32) ----
        const int m = (lane < ROWS) ? (mrow[j0 + lane] != 0) : 0;
        const unsigned long long sbits = __ballot(m);

        const f32x4* xrow = reinterpret_cast<const f32x4*>(x) +
                            ((size_t)b * T + j0) * (size_t)D4;
        f32x4* obase = reinterpret_cast<f32x4*>(out) + (size_t)b * T * (size_t)D4;
        const f32x4 z = {0.f, 0.f, 0.f, 0.f};

        // ---- copy: i-th selected row -> output row P+i. Wave w handles
        // i = w, w+NW, w+2NW, ... ; 2 rows per iteration for MLP.
        unsigned long long s = sbits;
        for (int k = 0; k < wave && s; ++k) s &= s - 1;  // skip to this wave's first
        int i = wave;
        while (s) {
            const int r0 = (int)__builtin_ctzll(s);
            unsigned long long s2 = s;
            #pragma unroll
            for (int k = 0; k < NW; ++k) s2 &= s2 - 1;  // pop NW bits
            const bool h2 = (s2 != 0);
            const int r1 = h2 ? (int)__builtin_ctzll(s2) : 0;
            for (int t = lane; t < D4; t += 64) {
                const f32x4 v0 = xrow[(size_t)r0 * D4 + t];
                f32x4 v1 = z;
                if (h2) v1 = xrow[(size_t)r1 * D4 + t];
                obase[(size_t)(P + i) * D4 + t] = v0;
                if (h2) obase[(size_t)(P + i + NW) * D4 + t] = v1;
            }
            unsigned long long s3 = s2;
            #pragma unroll
            for (int k = 0; k < NW; ++k) s3 &= s3 - 1;  // pop NW more
            s = s3;
            i += 2 * NW;
        }

        // ---- zero-pad rows >= L within this chunk's output range ----
        const int zstart = (L > j0) ? L : j0;
        for (int j = zstart + wave; j < j0 + ROWS; j += NW)
            for (int t = lane; t < D4; t += 64)
                obase[(size_t)j * D4 + t] = z;

        // ---- steal next chunk ----
        if (tid == 0) sChunk = (int)(gridDim.x + atomicAdd(counter, 1u));
        __syncthreads();  // publishes sChunk; also protects wred reuse
        id = sChunk;
    }
}

extern "C" void kernel_launch(void* const* d_in, const int* in_sizes, int n_in,
                              void* d_out, int out_size, void* d_ws, size_t ws_size,
                              hipStream_t stream) {
    const float* x = (const float*)d_in[0];
    const int* mask = (const int*)d_in[1];

    const int Nx = in_sizes[0];   // B*T*D
    const int BT = in_sizes[1];   // B*T
    const int B = out_size - Nx;  // lens appended after x_
    const int T = BT / B;
    const int D = Nx / BT;
    const int D4 = D / 4;
    const int CPB = T / ROWS;     // chunks per batch row
    const int total = B * CPB;

    float* out = (float*)d_out;
    float* lens_f = out + (size_t)Nx;
    unsigned* counter = (unsigned*)d_ws;

    hipMemsetAsync(counter, 0, sizeof(unsigned), stream);

    int blocks = 512;
    if (blocks > total) blocks = total;
    pad_masked_steal<<<blocks, BLK, 0, stream>>>(
        x, mask, out, lens_f, counter, T, D4, CPB, total);
}

// Round 7
// 21.107 us; speedup vs baseline: 1.8708x; 1.8708x over previous
//
#include <hip/hip_runtime.h>

// PadMaskedSequence, single fused kernel, one block per (batch, chunk-of-64-rows).
// d_out layout: x_ [B*T*D] f32, then lens [B] as float.
//
// GRID IS (B, CPB) with b = blockIdx.x (inner), c = blockIdx.y: linear block
// id = b + B*c, so the round-robin block->CU distribution gives each CU a
// uniform SPREAD of chunk indices c (c-quartiles), i.e. ~2 data-heavy + ~2
// zero-heavy chunks per CU. With grid (CPB, B) every CU got 4 blocks of the
// SAME c (256 % 64 == 0) -> systematic 1.33x worst-CU imbalance (R3/R4's
// stable ~22 us).
//
// Each block independently: (1) reads the L2-resident mask row once, reducing
// BOTH prefix-popcount P = sum(mask[0:c*64)) and total L = sum(mask[0:T)) in
// one packed 64-bit shuffle reduction; (2) wave 0 compacts the chunk's
// selected rows into an LDS list; (3) all waves copy the listed rows to
// output rows P+i (2-unrolled for ILP); (4) zero-pads output rows
// [max(j0,L), j0+64). Every output row written exactly once; no inter-block
// communication.

typedef float f32x4 __attribute__((ext_vector_type(4)));

#define BLK 256
#define NW (BLK / 64)
#define ROWS 64

__global__ __launch_bounds__(BLK) void pad_masked_fused(
    const float* __restrict__ x,
    const int* __restrict__ mask,
    float* __restrict__ out,
    float* __restrict__ lens_f,
    int T, int D4) {

    const int b = blockIdx.x;   // batch (inner grid dim!)
    const int c = blockIdx.y;   // chunk of ROWS rows
    const int tid = threadIdx.x;
    const int lane = tid & 63;
    const int wave = tid >> 6;
    const int j0 = c * ROWS;

    const int* mrow = mask + (size_t)b * T;

    // ---- packed popcount: pre = sum mask[0:j0), all = sum mask[0:T) ----
    // j0 % 64 == 0 and e % 4 == 0, so an int4 never straddles j0.
    int pre = 0, all = 0;
    for (int e = tid * 4; e < T; e += BLK * 4) {
        const int4 mv = *reinterpret_cast<const int4*>(mrow + e);
        const int s4 = (mv.x != 0) + (mv.y != 0) + (mv.z != 0) + (mv.w != 0);
        all += s4;
        if (e < j0) pre += s4;
    }
    unsigned long long packed = (unsigned long long)(unsigned)pre |
                                ((unsigned long long)(unsigned)all << 32);
    #pragma unroll
    for (int off = 32; off; off >>= 1) packed += __shfl_xor(packed, off);

    __shared__ unsigned long long wred[NW];
    __shared__ int selRows[ROWS];
    __shared__ int nsel;
    if (lane == 0) wred[wave] = packed;
    __syncthreads();

    unsigned long long tot = 0;
    #pragma unroll
    for (int w = 0; w < NW; ++w) tot += wred[w];
    const int P = (int)(tot & 0xffffffffull);  // output base row for this chunk
    const int L = (int)(tot >> 32);            // lens[b]

    // ---- wave 0: compact selected rows of this chunk into a list ----
    if (wave == 0) {
        const int m = (mrow[j0 + lane] != 0);
        int incl = m;
        #pragma unroll
        for (int off = 1; off < 64; off <<= 1) {
            const int v = __shfl_up(incl, off);
            if (lane >= off) incl += v;
        }
        if (m) selRows[incl - 1] = lane;
        if (lane == 63) nsel = incl;
    }
    __syncthreads();
    const int n = nsel;

    if (c == 0 && tid == 0) lens_f[b] = (float)L;

    const f32x4* xrow = reinterpret_cast<const f32x4*>(x) +
                        ((size_t)b * T + j0) * (size_t)D4;
    f32x4* obase = reinterpret_cast<f32x4*>(out) + (size_t)b * T * (size_t)D4;
    const f32x4 z = {0.f, 0.f, 0.f, 0.f};

    // ---- copy selected rows, 2-unrolled (two independent loads, two stores) ----
    for (int i = wave; i < n; i += 2 * NW) {
        const int i2 = i + NW;
        const bool h2 = (i2 < n);
        const int r0 = selRows[i];
        const int r1 = h2 ? selRows[i2] : 0;
        for (int t = lane; t < D4; t += 64) {
            const f32x4 v0 = xrow[(size_t)r0 * D4 + t];
            f32x4 v1 = z;
            if (h2) v1 = xrow[(size_t)r1 * D4 + t];
            obase[(size_t)(P + i) * D4 + t] = v0;
            if (h2) obase[(size_t)(P + i2) * D4 + t] = v1;
        }
    }

    // ---- zero-pad rows >= L within this chunk's output range ----
    const int zstart = (L > j0) ? L : j0;
    for (int j = zstart + wave; j < j0 + ROWS; j += NW) {
        for (int t = lane; t < D4; t += 64)
            obase[(size_t)j * D4 + t] = z;
    }
}

extern "C" void kernel_launch(void* const* d_in, const int* in_sizes, int n_in,
                              void* d_out, int out_size, void* d_ws, size_t ws_size,
                              hipStream_t stream) {
    const float* x = (const float*)d_in[0];
    const int* mask = (const int*)d_in[1];

    const int Nx = in_sizes[0];   // B*T*D
    const int BT = in_sizes[1];   // B*T
    const int B = out_size - Nx;  // lens appended after x_
    const int T = BT / B;
    const int D = Nx / BT;
    const int D4 = D / 4;

    float* out = (float*)d_out;
    float* lens_f = out + (size_t)Nx;

    dim3 grid(B, T / ROWS);  // b inner, c outer -> c-spread per CU
    pad_masked_fused<<<grid, BLK, 0, stream>>>(x, mask, out, lens_f, T, D4);
}

// Round 8
// 19.659 us; speedup vs baseline: 2.0086x; 1.0737x over previous
//
#include <hip/hip_runtime.h>

// PadMaskedSequence, single fused kernel, one block per (batch, chunk-of-64-rows).
// d_out layout: x_ [B*T*D] f32, then lens [B] as float.
//
// Grid is (B, CPB): linear block id = b + B*c spreads chunk indices c across
// CUs (fixes the systematic per-CU imbalance seen with (CPB, B) grids).
//
// Pipelined block structure (T14 issue-early/consume-late):
//   1. load chunk's own 64 mask vals -> ballot (identical in all waves, no LDS)
//   2. issue ALL popcount int4 mask loads into regs mv[NITER]
//   3. extract this wave's selected rows from ballot, ISSUE up to PF row
//      loads of x into registers (f32x4 per lane, D4==64)
//   4. consume mv[] -> packed {pre,all} shuffle+LDS reduction -> P, L
//      (mask loads are older than x loads -> this wait leaves x in flight)
//   5. store prefetched rows to output rows P+i; residual loop for cnt>PF
//   6. zero-pad rows [max(j0,L), j0+64)
// Every output row written exactly once; no inter-block communication.

typedef float f32x4 __attribute__((ext_vector_type(4)));

#define BLK 256
#define NW (BLK / 64)
#define ROWS 64
#define PF 12

template <int NITER>
__global__ __launch_bounds__(BLK, 4) void pad_masked_pipe(
    const float* __restrict__ x,
    const int* __restrict__ mask,
    float* __restrict__ out,
    float* __restrict__ lens_f,
    int T, int D4) {  // requires D4 == 64, T == NITER*BLK*4

    const int b = blockIdx.x;   // batch (inner grid dim)
    const int c = blockIdx.y;   // chunk of ROWS rows
    const int tid = threadIdx.x;
    const int lane = tid & 63;
    const int wave = tid >> 6;
    const int j0 = c * ROWS;

    const int* mrow = mask + (size_t)b * T;

    // (1) own-chunk mask value (issued first)
    const int msel = (mrow[j0 + lane] != 0);

    // (2) popcount loads into regs (issued before x loads)
    int4 mv[NITER];
    #pragma unroll
    for (int k = 0; k < NITER; ++k)
        mv[k] = *reinterpret_cast<const int4*>(mrow + (size_t)(tid + k * BLK) * 4);

    // (3) ballot + this wave's selected rows; issue x row loads into regs
    const unsigned long long sel = __ballot(msel);
    const f32x4* xrow = reinterpret_cast<const f32x4*>(x) +
                        ((size_t)b * T + j0) * (size_t)D4;

    unsigned long long t = sel;
    #pragma unroll
    for (int k = 0; k < NW - 1; ++k)
        if (k < wave) t &= t - 1;  // skip to this wave's first selected row

    f32x4 v[PF];
    int cnt = 0;
    #pragma unroll
    for (int k = 0; k < PF; ++k) {
        if (t) {
            const int r = (int)__builtin_ctzll(t);
            v[k] = xrow[(size_t)r * 64 + lane];
            cnt = k + 1;
            #pragma unroll
            for (int p = 0; p < NW; ++p) t &= t - 1;  // advance NW selected rows
        }
    }

    // (4) consume popcount loads: pre = sum[0:j0), all = sum[0:T)
    int pre = 0, all = 0;
    #pragma unroll
    for (int k = 0; k < NITER; ++k) {
        const int4 m4 = mv[k];
        const int s4 = (m4.x != 0) + (m4.y != 0) + (m4.z != 0) + (m4.w != 0);
        all += s4;
        if ((tid + k * BLK) * 4 < j0) pre += s4;
    }
    unsigned long long packed = (unsigned long long)(unsigned)pre |
                                ((unsigned long long)(unsigned)all << 32);
    #pragma unroll
    for (int off = 32; off; off >>= 1) packed += __shfl_xor(packed, off);

    __shared__ unsigned long long wred[NW];
    if (lane == 0) wred[wave] = packed;
    __syncthreads();
    unsigned long long tot = 0;
    #pragma unroll
    for (int w = 0; w < NW; ++w) tot += wred[w];
    const int P = (int)(tot & 0xffffffffull);
    const int L = (int)(tot >> 32);

    if (c == 0 && tid == 0) lens_f[b] = (float)L;

    // (5) store prefetched rows: i-th selected row -> output row P+i,
    // this wave owns i = wave + k*NW
    f32x4* obase = reinterpret_cast<f32x4*>(out) + (size_t)b * T * (size_t)D4;
    #pragma unroll
    for (int k = 0; k < PF; ++k)
        if (k < cnt)
            obase[(size_t)(P + wave + k * NW) * 64 + lane] = v[k];
    // residual rows (rare: > PF rows for this wave)
    int i = wave + PF * NW;
    while (t) {
        const int r = (int)__builtin_ctzll(t);
        #pragma unroll
        for (int p = 0; p < NW; ++p) t &= t - 1;
        obase[(size_t)(P + i) * 64 + lane] = xrow[(size_t)r * 64 + lane];
        i += NW;
    }

    // (6) zero-pad rows >= L in this chunk's output range
    const f32x4 z = {0.f, 0.f, 0.f, 0.f};
    const int zstart = (L > j0) ? L : j0;
    for (int j = zstart + wave; j < j0 + ROWS; j += NW)
        obase[(size_t)j * 64 + lane] = z;
}

// Generic fallback (R7 structure) for shapes the fast path doesn't cover.
__global__ __launch_bounds__(BLK) void pad_masked_fused(
    const float* __restrict__ x,
    const int* __restrict__ mask,
    float* __restrict__ out,
    float* __restrict__ lens_f,
    int T, int D4) {

    const int b = blockIdx.x;
    const int c = blockIdx.y;
    const int tid = threadIdx.x;
    const int lane = tid & 63;
    const int wave = tid >> 6;
    const int j0 = c * ROWS;

    const int* mrow = mask + (size_t)b * T;

    int pre = 0, all = 0;
    for (int e = tid * 4; e < T; e += BLK * 4) {
        const int4 mv = *reinterpret_cast<const int4*>(mrow + e);
        const int s4 = (mv.x != 0) + (mv.y != 0) + (mv.z != 0) + (mv.w != 0);
        all += s4;
        if (e < j0) pre += s4;
    }
    unsigned long long packed = (unsigned long long)(unsigned)pre |
                                ((unsigned long long)(unsigned)all << 32);
    #pragma unroll
    for (int off = 32; off; off >>= 1) packed += __shfl_xor(packed, off);

    __shared__ unsigned long long wred[NW];
    __shared__ int selRows[ROWS];
    __shared__ int nsel;
    if (lane == 0) wred[wave] = packed;
    __syncthreads();
    unsigned long long tot = 0;
    #pragma unroll
    for (int w = 0; w < NW; ++w) tot += wred[w];
    const int P = (int)(tot & 0xffffffffull);
    const int L = (int)(tot >> 32);

    if (wave == 0) {
        const int m = (mrow[j0 + lane] != 0);
        int incl = m;
        #pragma unroll
        for (int off = 1; off < 64; off <<= 1) {
            const int v = __shfl_up(incl, off);
            if (lane >= off) incl += v;
        }
        if (m) selRows[incl - 1] = lane;
        if (lane == 63) nsel = incl;
    }
    __syncthreads();
    const int n = nsel;

    if (c == 0 && tid == 0) lens_f[b] = (float)L;

    const f32x4* xrow = reinterpret_cast<const f32x4*>(x) +
                        ((size_t)b * T + j0) * (size_t)D4;
    f32x4* obase = reinterpret_cast<f32x4*>(out) + (size_t)b * T * (size_t)D4;
    const f32x4 z = {0.f, 0.f, 0.f, 0.f};

    for (int i = wave; i < n; i += 2 * NW) {
        const int i2 = i + NW;
        const bool h2 = (i2 < n);
        const int r0 = selRows[i];
        const int r1 = h2 ? selRows[i2] : 0;
        for (int tt = lane; tt < D4; tt += 64) {
            const f32x4 v0 = xrow[(size_t)r0 * D4 + tt];
            f32x4 v1 = z;
            if (h2) v1 = xrow[(size_t)r1 * D4 + tt];
            obase[(size_t)(P + i) * D4 + tt] = v0;
            if (h2) obase[(size_t)(P + i2) * D4 + tt] = v1;
        }
    }

    const int zstart = (L > j0) ? L : j0;
    for (int j = zstart + wave; j < j0 + ROWS; j += NW)
        for (int tt = lane; tt < D4; tt += 64)
            obase[(size_t)j * D4 + tt] = z;
}

extern "C" void kernel_launch(void* const* d_in, const int* in_sizes, int n_in,
                              void* d_out, int out_size, void* d_ws, size_t ws_size,
                              hipStream_t stream) {
    const float* x = (const float*)d_in[0];
    const int* mask = (const int*)d_in[1];

    const int Nx = in_sizes[0];   // B*T*D
    const int BT = in_sizes[1];   // B*T
    const int B = out_size - Nx;  // lens appended after x_
    const int T = BT / B;
    const int D = Nx / BT;
    const int D4 = D / 4;

    float* out = (float*)d_out;
    float* lens_f = out + (size_t)Nx;

    dim3 grid(B, T / ROWS);  // b inner, c outer -> c-spread per CU

    const int niter = T / (BLK * 4);
    const bool fast = (D4 == 64) && (T % (BLK * 4) == 0) && (T % ROWS == 0);
    if (fast && niter == 4)
        pad_masked_pipe<4><<<grid, BLK, 0, stream>>>(x, mask, out, lens_f, T, D4);
    else if (fast && niter == 2)
        pad_masked_pipe<2><<<grid, BLK, 0, stream>>>(x, mask, out, lens_f, T, D4);
    else if (fast && niter == 1)
        pad_masked_pipe<1><<<grid, BLK, 0, stream>>>(x, mask, out, lens_f, T, D4);
    else if (fast && niter == 8)
        pad_masked_pipe<8><<<grid, BLK, 0, stream>>>(x, mask, out, lens_f, T, D4);
    else
        pad_masked_fused<<<grid, BLK, 0, stream>>>(x, mask, out, lens_f, T, D4);
}

// Round 9
// 19.427 us; speedup vs baseline: 2.0325x; 1.0119x over previous
//
#include <hip/hip_runtime.h>

// PadMaskedSequence, single fused kernel, one block per (batch, chunk-of-64-rows).
// d_out layout: x_ [B*T*D] f32, then lens [B] as float.
//
// Grid (B, CPB): linear id = b + B*c spreads chunk indices across CUs.
//
// Balanced-pad scheme: chunk c writes its n selected rows to output rows
// [P, P+n) AND exactly (64-n) pad rows [T-64(c+1)+P+n, T-64c+P).
// Telescoping over c tiles [L, T) exactly once -> every block writes exactly
// 64 rows (perfect write balance), and only the PREFIX popcount P is needed
// (no full-row total). lens = P + n of the last chunk.
//
// Pipeline (straight-line, precise vmcnt):
//   1. issue own-chunk mask load (msel)
//   2. issue NITER int4 mask loads (full row, unconditional, straight-line)
//   3. ballot(msel)  -- waits only the oldest load, mv[] stays in flight
//   4. issue PF=12 UNCONDITIONAL x-row loads (clamped index; row-0 dups hit L1)
//   5. consume mv[] -> pre (masked by e<j0), shuffle+LDS reduce -> P
//   6. store prefetched rows to [P + wave + k*NW]; residual loop if n > 48
//   7. write (64-n) zero rows; last chunk writes lens

typedef float f32x4 __attribute__((ext_vector_type(4)));

#define BLK 256
#define NW (BLK / 64)
#define ROWS 64
#define PF 12

template <int NITER>
__global__ __launch_bounds__(BLK, 4) void pad_masked_pipe(
    const float* __restrict__ x,
    const int* __restrict__ mask,
    float* __restrict__ out,
    float* __restrict__ lens_f,
    int T, int CPB) {  // requires D4 == 64, T == NITER*BLK*4, ROWS == 64

    const int b = blockIdx.x;   // batch (inner grid dim)
    const int c = blockIdx.y;   // chunk of ROWS rows
    const int tid = threadIdx.x;
    const int lane = tid & 63;
    const int wave = tid >> 6;
    const int j0 = c * ROWS;

    const int* mrow = mask + (size_t)b * T;

    // (1) own-chunk mask value -- issued first, ballot waits only on this
    const int msel = (mrow[j0 + lane] != 0);

    // (2) full-row mask loads, straight-line into regs
    int4 mv[NITER];
    #pragma unroll
    for (int k = 0; k < NITER; ++k)
        mv[k] = *reinterpret_cast<const int4*>(mrow + (size_t)(tid + k * BLK) * 4);

    // (3) ballot: selected rows of this chunk (wave-uniform)
    const unsigned long long sel = __ballot(msel);
    const int n = (int)__popcll(sel);

    // (4) unconditional prefetch of this wave's selected rows
    const f32x4* xrow = reinterpret_cast<const f32x4*>(x) +
                        ((size_t)b * T + j0) * (size_t)64;
    unsigned long long t = sel;
    #pragma unroll
    for (int k = 0; k < NW - 1; ++k)
        if (k < wave) t &= t - 1;          // skip to this wave's first bit

    int rk[PF];
    {
        unsigned long long u = t;
        #pragma unroll
        for (int k = 0; k < PF; ++k) {
            rk[k] = u ? (int)__builtin_ctzll(u) : 0;   // cndmask, no branch
            #pragma unroll
            for (int p = 0; p < NW; ++p) u &= u - 1;   // advance NW bits
        }
        t = u;  // residual bits (rows beyond PF per wave)
    }
    f32x4 v[PF];
    #pragma unroll
    for (int k = 0; k < PF; ++k)
        v[k] = xrow[(size_t)rk[k] * 64 + lane];        // unconditional

    // (5) prefix popcount: pre = sum mask[0:j0)
    int pre = 0;
    #pragma unroll
    for (int k = 0; k < NITER; ++k) {
        const int4 m4 = mv[k];
        const int e = (tid + k * BLK) * 4;             // e % 4 == 0, j0 % 64 == 0
        if (e < j0) pre += (m4.x != 0) + (m4.y != 0) + (m4.z != 0) + (m4.w != 0);
    }
    #pragma unroll
    for (int off = 32; off; off >>= 1) pre += __shfl_xor(pre, off);

    __shared__ int wred[NW];
    if (lane == 0) wred[wave] = pre;
    __syncthreads();
    const int P = wred[0] + wred[1] + wred[2] + wred[3];

    // (6) store prefetched data rows: i-th selected row -> output row P+i,
    // wave owns i = wave + k*NW
    f32x4* obase = reinterpret_cast<f32x4*>(out) + (size_t)b * T * (size_t)64;
    const int cnt = (n > wave) ? ((n - wave - 1) / NW + 1) : 0;
    #pragma unroll
    for (int k = 0; k < PF; ++k)
        if (k < cnt)
            obase[(size_t)(P + wave + k * NW) * 64 + lane] = v[k];
    // residual rows (n > PF*NW/... i.e. this wave has >PF selected rows)
    int i = wave + PF * NW;
    while (t) {
        const int r = (int)__builtin_ctzll(t);
        #pragma unroll
        for (int p = 0; p < NW; ++p) t &= t - 1;
        obase[(size_t)(P + i) * 64 + lane] = xrow[(size_t)r * 64 + lane];
        i += NW;
    }

    // (7) balanced zero-pad: rows [T - 64(c+1) + P + n, T - 64c + P)
    const f32x4 z = {0.f, 0.f, 0.f, 0.f};
    const int pend = T - c * ROWS + P;
    for (int j = pend - (ROWS - n) + wave; j < pend; j += NW)
        obase[(size_t)j * 64 + lane] = z;

    // last chunk knows lens = P + n
    if (c == CPB - 1 && tid == 0) lens_f[b] = (float)(P + n);
}

// Generic fallback for shapes the fast path doesn't cover (original scheme).
__global__ __launch_bounds__(BLK) void pad_masked_fused(
    const float* __restrict__ x,
    const int* __restrict__ mask,
    float* __restrict__ out,
    float* __restrict__ lens_f,
    int T, int D4) {

    const int b = blockIdx.x;
    const int c = blockIdx.y;
    const int tid = threadIdx.x;
    const int lane = tid & 63;
    const int wave = tid >> 6;
    const int j0 = c * ROWS;

    const int* mrow = mask + (size_t)b * T;

    int pre = 0, all = 0;
    for (int e = tid * 4; e < T; e += BLK * 4) {
        const int4 mv = *reinterpret_cast<const int4*>(mrow + e);
        const int s4 = (mv.x != 0) + (mv.y != 0) + (mv.z != 0) + (mv.w != 0);
        all += s4;
        if (e < j0) pre += s4;
    }
    unsigned long long packed = (unsigned long long)(unsigned)pre |
                                ((unsigned long long)(unsigned)all << 32);
    #pragma unroll
    for (int off = 32; off; off >>= 1) packed += __shfl_xor(packed, off);

    __shared__ unsigned long long wred[NW];
    __shared__ int selRows[ROWS];
    __shared__ int nsel;
    if (lane == 0) wred[wave] = packed;
    __syncthreads();
    unsigned long long tot = 0;
    #pragma unroll
    for (int w = 0; w < NW; ++w) tot += wred[w];
    const int P = (int)(tot & 0xffffffffull);
    const int L = (int)(tot >> 32);

    if (wave == 0) {
        const int m = (mrow[j0 + lane] != 0);
        int incl = m;
        #pragma unroll
        for (int off = 1; off < 64; off <<= 1) {
            const int vv = __shfl_up(incl, off);
            if (lane >= off) incl += vv;
        }
        if (m) selRows[incl - 1] = lane;
        if (lane == 63) nsel = incl;
    }
    __syncthreads();
    const int n = nsel;

    if (c == 0 && tid == 0) lens_f[b] = (float)L;

    const f32x4* xrow = reinterpret_cast<const f32x4*>(x) +
                        ((size_t)b * T + j0) * (size_t)D4;
    f32x4* obase = reinterpret_cast<f32x4*>(out) + (size_t)b * T * (size_t)D4;
    const f32x4 z = {0.f, 0.f, 0.f, 0.f};

    for (int i = wave; i < n; i += NW) {
        const int r0 = selRows[i];
        for (int tt = lane; tt < D4; tt += 64)
            obase[(size_t)(P + i) * D4 + tt] = xrow[(size_t)r0 * D4 + tt];
    }

    const int zstart = (L > j0) ? L : j0;
    for (int j = zstart + wave; j < j0 + ROWS; j += NW)
        for (int tt = lane; tt < D4; tt += 64)
            obase[(size_t)j * D4 + tt] = z;
}

extern "C" void kernel_launch(void* const* d_in, const int* in_sizes, int n_in,
                              void* d_out, int out_size, void* d_ws, size_t ws_size,
                              hipStream_t stream) {
    const float* x = (const float*)d_in[0];
    const int* mask = (const int*)d_in[1];

    const int Nx = in_sizes[0];   // B*T*D
    const int BT = in_sizes[1];   // B*T
    const int B = out_size - Nx;  // lens appended after x_
    const int T = BT / B;
    const int D = Nx / BT;
    const int D4 = D / 4;
    const int CPB = T / ROWS;

    float* out = (float*)d_out;
    float* lens_f = out + (size_t)Nx;

    dim3 grid(B, CPB);  // b inner, c outer -> c-spread per CU

    const int niter = T / (BLK * 4);
    const bool fast = (D4 == 64) && (T % (BLK * 4) == 0) && (T % ROWS == 0);
    if (fast && niter == 4)
        pad_masked_pipe<4><<<grid, BLK, 0, stream>>>(x, mask, out, lens_f, T, CPB);
    else if (fast && niter == 2)
        pad_masked_pipe<2><<<grid, BLK, 0, stream>>>(x, mask, out, lens_f, T, CPB);
    else if (fast && niter == 1)
        pad_masked_pipe<1><<<grid, BLK, 0, stream>>>(x, mask, out, lens_f, T, CPB);
    else if (fast && niter == 8)
        pad_masked_pipe<8><<<grid, BLK, 0, stream>>>(x, mask, out, lens_f, T, CPB);
    else
        pad_masked_fused<<<grid, BLK, 0, stream>>>(x, mask, out, lens_f, T, D4);
}